// Round 1
// baseline (2958.582 us; speedup 1.0000x reference)
//
#include <hip/hip_runtime.h>

// GCN layer on MI355X:
//   agg = scatter_mean(x[src] -> dst)        (fused: aggregate x, not h=xW+b)
//   out = relu(BN_eval(agg @ W + b))
// Linearity lets us swap aggregate<->linear: mean(h[src]) = mean(x[src])@W + b.
// Edge sums accumulate directly into d_out (exactly N*C floats); GEMM+BN+ReLU
// then runs in-place (each block stages all its input rows in LDS before
// writing the same rows back).

#define NN 100000
#define NE 1600000
#define CC 128
#define BN_EPS 1e-5f

// ---------------------------------------------------------------------------
// Edge scatter: 32 lanes per edge, float4 per lane (32*16B = 512B row).
// Native fp32 atomics (unsafeAtomicAdd -> global_atomic_add_f32, no return).
// ---------------------------------------------------------------------------
__global__ __launch_bounds__(256) void edge_scatter(
    const float* __restrict__ x, const int* __restrict__ ei,
    float* __restrict__ sums, int* __restrict__ cnt) {
  int gt = blockIdx.x * 256 + threadIdx.x;
  int e = gt >> 5;          // 32 threads per edge
  int sub = gt & 31;        // which 16B chunk of the 512B row
  if (e >= NE) return;
  int src = ei[e];
  int dst = ei[NE + e];
  const float4 v = *(const float4*)(x + (size_t)src * CC + sub * 4);
  float* o = sums + (size_t)dst * CC + sub * 4;
  unsafeAtomicAdd(o + 0, v.x);
  unsafeAtomicAdd(o + 1, v.y);
  unsafeAtomicAdd(o + 2, v.z);
  unsafeAtomicAdd(o + 3, v.w);
  if (sub == 0) atomicAdd(cnt + dst, 1);
}

// ---------------------------------------------------------------------------
// GEMM (fp32 vector ALU; no fp32 MFMA on CDNA4) + fused mean-div + BN + ReLU.
// Tile: 64 nodes x 128 cols per 256-thread block.
// Thread t: cg = t&31 -> cols cg*4..+3 ; ng = t>>5 -> nodes ng*8..+7.
// LDS xsT[k][n] (stride 65: odd -> spread banks; scalar reads are broadcast).
// Per k: 1 global float4 (W row chunk, L1/L2-resident) + 8 LDS b32 + 32 FMA
// -> FMA-bound (64 cyc FMA vs ~46 cyc LDS per wave per k).
// In-place: buf is both sums (input) and out (output).
// ---------------------------------------------------------------------------
__global__ __launch_bounds__(256) void gemm_bn_relu(
    float* buf, const float* __restrict__ W, const float* __restrict__ bias,
    const float* __restrict__ gamma, const float* __restrict__ beta,
    const float* __restrict__ rmean, const float* __restrict__ rvar,
    const int* __restrict__ cnt) {
  __shared__ float xsT[CC][65];  // [k][node], 128*65*4 = 33.3 KB -> 4 blocks/CU
  const int t = threadIdx.x;
  const int n0 = blockIdx.x * 64;

  // Load 64 rows x 128 cols, transposing into xsT. Coalesced float4 reads:
  // flat float4 index i = t + 256*j ; row = i/32 ; k-offset = (i%32)*4.
  for (int j = 0; j < 8; ++j) {
    int i = t + 256 * j;
    int row = i >> 5;
    int ko = (i & 31) * 4;
    float4 v = make_float4(0.f, 0.f, 0.f, 0.f);
    if (n0 + row < NN) v = *(const float4*)(buf + (size_t)(n0 + row) * CC + ko);
    xsT[ko + 0][row] = v.x;
    xsT[ko + 1][row] = v.y;
    xsT[ko + 2][row] = v.z;
    xsT[ko + 3][row] = v.w;
  }
  __syncthreads();

  const int cg = t & 31;   // col group
  const int ng = t >> 5;   // node group
  const int ng8 = ng * 8;

  float acc[8][4];
#pragma unroll
  for (int j = 0; j < 8; ++j)
#pragma unroll
    for (int c = 0; c < 4; ++c) acc[j][c] = 0.f;

#pragma unroll 8
  for (int k = 0; k < CC; ++k) {
    const float4 wv = *(const float4*)(W + k * CC + cg * 4);
#pragma unroll
    for (int j = 0; j < 8; ++j) {
      const float xv = xsT[k][ng8 + j];
      acc[j][0] = fmaf(xv, wv.x, acc[j][0]);
      acc[j][1] = fmaf(xv, wv.y, acc[j][1]);
      acc[j][2] = fmaf(xv, wv.z, acc[j][2]);
      acc[j][3] = fmaf(xv, wv.w, acc[j][3]);
    }
  }

  // Epilogue: val = acc/max(cnt,1) + b (b only if cnt>0, matching ref's
  // agg==0 for isolated nodes), then BN(eval) + ReLU.
  const float4 bb = *(const float4*)(bias + cg * 4);
  const float4 gg = *(const float4*)(gamma + cg * 4);
  const float4 bt = *(const float4*)(beta + cg * 4);
  const float4 mu = *(const float4*)(rmean + cg * 4);
  const float4 vr = *(const float4*)(rvar + cg * 4);
  float sc[4], sh[4], bv[4];
  sc[0] = gg.x * rsqrtf(vr.x + BN_EPS);
  sc[1] = gg.y * rsqrtf(vr.y + BN_EPS);
  sc[2] = gg.z * rsqrtf(vr.z + BN_EPS);
  sc[3] = gg.w * rsqrtf(vr.w + BN_EPS);
  sh[0] = bt.x - mu.x * sc[0];
  sh[1] = bt.y - mu.y * sc[1];
  sh[2] = bt.z - mu.z * sc[2];
  sh[3] = bt.w - mu.w * sc[3];
  bv[0] = bb.x; bv[1] = bb.y; bv[2] = bb.z; bv[3] = bb.w;

#pragma unroll
  for (int j = 0; j < 8; ++j) {
    const int n = n0 + ng8 + j;
    if (n >= NN) continue;
    const int cn = cnt[n];
    const float inv = cn > 0 ? 1.0f / (float)cn : 0.0f;
    const float bsel = cn > 0 ? 1.0f : 0.0f;
    float4 o;
    o.x = fmaxf(0.f, (acc[j][0] * inv + bsel * bv[0]) * sc[0] + sh[0]);
    o.y = fmaxf(0.f, (acc[j][1] * inv + bsel * bv[1]) * sc[1] + sh[1]);
    o.z = fmaxf(0.f, (acc[j][2] * inv + bsel * bv[2]) * sc[2] + sh[2]);
    o.w = fmaxf(0.f, (acc[j][3] * inv + bsel * bv[3]) * sc[3] + sh[3]);
    *(float4*)(buf + (size_t)n * CC + cg * 4) = o;
  }
}

extern "C" void kernel_launch(void* const* d_in, const int* in_sizes, int n_in,
                              void* d_out, int out_size, void* d_ws, size_t ws_size,
                              hipStream_t stream) {
  const float* x     = (const float*)d_in[0];
  const int*   ei    = (const int*)d_in[1];
  const float* W     = (const float*)d_in[2];
  const float* bias  = (const float*)d_in[3];
  const float* gamma = (const float*)d_in[4];
  const float* beta  = (const float*)d_in[5];
  const float* rmean = (const float*)d_in[6];
  const float* rvar  = (const float*)d_in[7];
  float* out = (float*)d_out;
  int*   cnt = (int*)d_ws;

  // Zero the accumulators (d_out is re-poisoned 0xAA before every call).
  hipMemsetAsync(out, 0, (size_t)NN * CC * sizeof(float), stream);
  hipMemsetAsync(cnt, 0, (size_t)NN * sizeof(int), stream);

  // Scatter-add x rows onto destination nodes + degree counts.
  edge_scatter<<<(NE * 32) / 256, 256, 0, stream>>>(x, ei, out, cnt);

  // In-place GEMM + mean + BN + ReLU.
  gemm_bn_relu<<<(NN + 63) / 64, 256, 0, stream>>>(out, W, bias, gamma, beta,
                                                   rmean, rvar, cnt);
}

// Round 2
// 525.773 us; speedup vs baseline: 5.6271x; 5.6271x over previous
//
#include <hip/hip_runtime.h>

// GCN layer on MI355X — round 2: kill the fp32 atomic scatter (74.7 G atomic/s
// pipe limit, 2743 us) by building CSR-by-dst on device, then gather-mean.
//   agg = gather_mean(x[csr[dst]])          (x is 51 MB -> LLC-resident reads)
//   out = relu(BN_eval(agg @ W + b))        (linearity: mean(h) = mean(x)@W+b)
// Edge pipeline: count -> 3-kernel scan -> csr fill -> gather. Gather writes
// every row of d_out, then GEMM+BN+ReLU runs in-place on d_out.

#define NN 100000
#define NE 1600000
#define CC 128
#define BN_EPS 1e-5f
#define NB 391  // ceil(NN/256)

// ---------------------------------------------------------------------------
// Phase 1: degree count. 1.6M int atomics (~75 G/s pipe -> ~21 us).
// ---------------------------------------------------------------------------
__global__ __launch_bounds__(256) void degree_count(const int* __restrict__ ei,
                                                    int* __restrict__ cnt) {
  int e = blockIdx.x * 256 + threadIdx.x;
  if (e >= NE) return;
  atomicAdd(cnt + ei[NE + e], 1);
}

// ---------------------------------------------------------------------------
// Phase 2: exclusive scan of cnt[NN] -> off[NN+1].  scan1: per-block scan +
// block sums; scan2: single-block scan of the 391 block sums; scan3: add.
// ---------------------------------------------------------------------------
__global__ __launch_bounds__(256) void scan1(const int* __restrict__ cnt,
                                             int* __restrict__ off,
                                             int* __restrict__ bsum) {
  __shared__ int sh[256];
  const int t = threadIdx.x;
  const int i = blockIdx.x * 256 + t;
  const int v = (i < NN) ? cnt[i] : 0;
  sh[t] = v;
  __syncthreads();
  for (int d = 1; d < 256; d <<= 1) {
    int add = (t >= d) ? sh[t - d] : 0;
    __syncthreads();
    sh[t] += add;
    __syncthreads();
  }
  if (i < NN) off[i] = sh[t] - v;  // exclusive
  if (t == 255) bsum[blockIdx.x] = sh[t];
}

__global__ __launch_bounds__(512) void scan2(int* __restrict__ bsum) {
  __shared__ int sh[512];
  const int t = threadIdx.x;
  const int v = (t < NB) ? bsum[t] : 0;
  sh[t] = v;
  __syncthreads();
  for (int d = 1; d < 512; d <<= 1) {
    int add = (t >= d) ? sh[t - d] : 0;
    __syncthreads();
    sh[t] += add;
    __syncthreads();
  }
  if (t < NB) bsum[t] = sh[t] - v;  // exclusive block offsets
}

__global__ __launch_bounds__(256) void scan3(int* __restrict__ off,
                                             const int* __restrict__ bsum) {
  const int i = blockIdx.x * 256 + threadIdx.x;
  if (i < NN) off[i] += bsum[blockIdx.x];
  if (i == 0) off[NN] = NE;
}

// ---------------------------------------------------------------------------
// Phase 3: CSR fill. cursor starts as a copy of off.
// ---------------------------------------------------------------------------
__global__ __launch_bounds__(256) void csr_fill(const int* __restrict__ ei,
                                                int* __restrict__ cursor,
                                                int* __restrict__ csr) {
  int e = blockIdx.x * 256 + threadIdx.x;
  if (e >= NE) return;
  int pos = atomicAdd(cursor + ei[NE + e], 1);
  csr[pos] = ei[e];  // store src
}

// ---------------------------------------------------------------------------
// Phase 4: gather-mean. One wave per dst node; lane l owns cols [2l, 2l+1].
// Per edge: one coalesced 512B row read (64 lanes x float2). x is 51.2 MB ->
// LLC-resident, so this runs at cache BW instead of the atomic pipe.
// 2-deep unroll for MLP on the csr->x dependent chain.
// ---------------------------------------------------------------------------
__global__ __launch_bounds__(256) void gather_mean(const float* __restrict__ x,
                                                   const int* __restrict__ off,
                                                   const int* __restrict__ csr,
                                                   float* __restrict__ agg) {
  const int wid = (blockIdx.x * 256 + threadIdx.x) >> 6;  // dst node
  const int lane = threadIdx.x & 63;
  if (wid >= NN) return;
  const int s = off[wid], e = off[wid + 1];
  const float* xb = x + lane * 2;
  float2 acc = make_float2(0.f, 0.f);
  int i = s;
  for (; i + 1 < e; i += 2) {
    int s0 = csr[i], s1 = csr[i + 1];
    float2 a = *(const float2*)(xb + (size_t)s0 * CC);
    float2 b = *(const float2*)(xb + (size_t)s1 * CC);
    acc.x += a.x + b.x;
    acc.y += a.y + b.y;
  }
  if (i < e) {
    int s0 = csr[i];
    float2 a = *(const float2*)(xb + (size_t)s0 * CC);
    acc.x += a.x;
    acc.y += a.y;
  }
  const float inv = (e > s) ? 1.0f / (float)(e - s) : 0.0f;
  acc.x *= inv;
  acc.y *= inv;
  *(float2*)(agg + (size_t)wid * CC + lane * 2) = acc;
}

// ---------------------------------------------------------------------------
// Fallback scatter path (only if ws_size is too small for CSR buffers).
// ---------------------------------------------------------------------------
__global__ __launch_bounds__(256) void edge_scatter(
    const float* __restrict__ x, const int* __restrict__ ei,
    float* __restrict__ sums, int* __restrict__ cnt) {
  int gt = blockIdx.x * 256 + threadIdx.x;
  int e = gt >> 5;
  int sub = gt & 31;
  if (e >= NE) return;
  int src = ei[e];
  int dst = ei[NE + e];
  const float4 v = *(const float4*)(x + (size_t)src * CC + sub * 4);
  float* o = sums + (size_t)dst * CC + sub * 4;
  unsafeAtomicAdd(o + 0, v.x);
  unsafeAtomicAdd(o + 1, v.y);
  unsafeAtomicAdd(o + 2, v.z);
  unsafeAtomicAdd(o + 3, v.w);
  if (sub == 0) atomicAdd(cnt + dst, 1);
}

// ---------------------------------------------------------------------------
// GEMM (fp32 vector ALU) + BN + ReLU, in-place on buf.
// PREMEANED=true: buf rows already divided by deg; deg>0 test via off[].
// PREMEANED=false (fallback): buf holds sums; divide by cnt[] here.
// ---------------------------------------------------------------------------
template <bool PREMEANED>
__global__ __launch_bounds__(256) void gemm_bn_relu(
    float* buf, const float* __restrict__ W, const float* __restrict__ bias,
    const float* __restrict__ gamma, const float* __restrict__ beta,
    const float* __restrict__ rmean, const float* __restrict__ rvar,
    const int* __restrict__ degptr) {
  __shared__ float xsT[CC][65];
  const int t = threadIdx.x;
  const int n0 = blockIdx.x * 64;

  for (int j = 0; j < 8; ++j) {
    int i = t + 256 * j;
    int row = i >> 5;
    int ko = (i & 31) * 4;
    float4 v = make_float4(0.f, 0.f, 0.f, 0.f);
    if (n0 + row < NN) v = *(const float4*)(buf + (size_t)(n0 + row) * CC + ko);
    xsT[ko + 0][row] = v.x;
    xsT[ko + 1][row] = v.y;
    xsT[ko + 2][row] = v.z;
    xsT[ko + 3][row] = v.w;
  }
  __syncthreads();

  const int cg = t & 31;
  const int ng8 = (t >> 5) * 8;

  float acc[8][4];
#pragma unroll
  for (int j = 0; j < 8; ++j)
#pragma unroll
    for (int c = 0; c < 4; ++c) acc[j][c] = 0.f;

#pragma unroll 8
  for (int k = 0; k < CC; ++k) {
    const float4 wv = *(const float4*)(W + k * CC + cg * 4);
#pragma unroll
    for (int j = 0; j < 8; ++j) {
      const float xv = xsT[k][ng8 + j];
      acc[j][0] = fmaf(xv, wv.x, acc[j][0]);
      acc[j][1] = fmaf(xv, wv.y, acc[j][1]);
      acc[j][2] = fmaf(xv, wv.z, acc[j][2]);
      acc[j][3] = fmaf(xv, wv.w, acc[j][3]);
    }
  }

  const float4 bb = *(const float4*)(bias + cg * 4);
  const float4 gg = *(const float4*)(gamma + cg * 4);
  const float4 bt = *(const float4*)(beta + cg * 4);
  const float4 mu = *(const float4*)(rmean + cg * 4);
  const float4 vr = *(const float4*)(rvar + cg * 4);
  float sc[4], sh[4], bv[4];
  sc[0] = gg.x * rsqrtf(vr.x + BN_EPS);
  sc[1] = gg.y * rsqrtf(vr.y + BN_EPS);
  sc[2] = gg.z * rsqrtf(vr.z + BN_EPS);
  sc[3] = gg.w * rsqrtf(vr.w + BN_EPS);
  sh[0] = bt.x - mu.x * sc[0];
  sh[1] = bt.y - mu.y * sc[1];
  sh[2] = bt.z - mu.z * sc[2];
  sh[3] = bt.w - mu.w * sc[3];
  bv[0] = bb.x; bv[1] = bb.y; bv[2] = bb.z; bv[3] = bb.w;

#pragma unroll
  for (int j = 0; j < 8; ++j) {
    const int n = n0 + ng8 + j;
    if (n >= NN) continue;
    float inv, bsel;
    if (PREMEANED) {
      const int deg = degptr[n + 1] - degptr[n];  // off[] diff
      inv = 1.0f;
      bsel = deg > 0 ? 1.0f : 0.0f;
    } else {
      const int cn = degptr[n];  // cnt[]
      inv = cn > 0 ? 1.0f / (float)cn : 0.0f;
      bsel = cn > 0 ? 1.0f : 0.0f;
    }
    float4 o;
    o.x = fmaxf(0.f, (acc[j][0] * inv + bsel * bv[0]) * sc[0] + sh[0]);
    o.y = fmaxf(0.f, (acc[j][1] * inv + bsel * bv[1]) * sc[1] + sh[1]);
    o.z = fmaxf(0.f, (acc[j][2] * inv + bsel * bv[2]) * sc[2] + sh[2]);
    o.w = fmaxf(0.f, (acc[j][3] * inv + bsel * bv[3]) * sc[3] + sh[3]);
    *(float4*)(buf + (size_t)n * CC + cg * 4) = o;
  }
}

extern "C" void kernel_launch(void* const* d_in, const int* in_sizes, int n_in,
                              void* d_out, int out_size, void* d_ws, size_t ws_size,
                              hipStream_t stream) {
  const float* x     = (const float*)d_in[0];
  const int*   ei    = (const int*)d_in[1];
  const float* W     = (const float*)d_in[2];
  const float* bias  = (const float*)d_in[3];
  const float* gamma = (const float*)d_in[4];
  const float* beta  = (const float*)d_in[5];
  const float* rmean = (const float*)d_in[6];
  const float* rvar  = (const float*)d_in[7];
  float* out = (float*)d_out;

  // ws layout (bytes): off[NN+1] | cnt/cursor[NN] | bsum[512] | csr[NE]
  const size_t OFF_B = 0;
  const size_t CNT_B = 400128;            // (NN+1)*4=400004, padded
  const size_t BSUM_B = 800256;
  const size_t CSR_B = 802304;
  const size_t NEED = CSR_B + (size_t)NE * 4;  // ~7.2 MB

  if (ws_size >= NEED) {
    int* off    = (int*)((char*)d_ws + OFF_B);
    int* cnt    = (int*)((char*)d_ws + CNT_B);  // reused as cursor after scan
    int* bsum   = (int*)((char*)d_ws + BSUM_B);
    int* csr    = (int*)((char*)d_ws + CSR_B);

    hipMemsetAsync(cnt, 0, (size_t)NN * sizeof(int), stream);
    degree_count<<<(NE + 255) / 256, 256, 0, stream>>>(ei, cnt);
    scan1<<<NB, 256, 0, stream>>>(cnt, off, bsum);
    scan2<<<1, 512, 0, stream>>>(bsum);
    scan3<<<NB, 256, 0, stream>>>(off, bsum);
    // cursor <- off (cnt region no longer needed as counts)
    hipMemcpyAsync(cnt, off, (size_t)NN * sizeof(int),
                   hipMemcpyDeviceToDevice, stream);
    csr_fill<<<(NE + 255) / 256, 256, 0, stream>>>(ei, cnt, csr);
    gather_mean<<<(NN * 64) / 256, 256, 0, stream>>>(x, off, csr, out);
    gemm_bn_relu<true><<<(NN + 63) / 64, 256, 0, stream>>>(
        out, W, bias, gamma, beta, rmean, rvar, off);
  } else {
    // Fallback: atomic scatter path (needs only cnt = 400 KB of ws).
    int* cnt = (int*)d_ws;
    hipMemsetAsync(out, 0, (size_t)NN * CC * sizeof(float), stream);
    hipMemsetAsync(cnt, 0, (size_t)NN * sizeof(int), stream);
    edge_scatter<<<(NE * 32) / 256, 256, 0, stream>>>(x, ei, out, cnt);
    gemm_bn_relu<false><<<(NN + 63) / 64, 256, 0, stream>>>(
        out, W, bias, gamma, beta, rmean, rvar, cnt);
  }
}

// Round 3
// 410.108 us; speedup vs baseline: 7.2142x; 1.2820x over previous
//
#include <hip/hip_runtime.h>

// GCN layer on MI355X — round 3.
// Pipeline (primary, ws >= ~33MB):
//   prep:     Wsw = bf16 MFMA-B-fragment-swizzled W; scsh = BN scale/shift
//   linear:   h = bf16(x @ W + b)  via mfma_f32_16x16x32_bf16  (into ws)
//   CSR:      degree -> scan -> fill (by dst)
//   gather:   out = relu(BN(mean(h[csr[dst]])))   (256B/edge bf16 rows)
// mean(h[src]) = mean(x[src])@W + b  (linearity); deg=0 -> sum=0 -> relu(sh),
// matching ref's agg=0 for isolated nodes (b appears once per edge in h).

#define NN 100000
#define NE 1600000
#define CC 128
#define BN_EPS 1e-5f
#define NB 391  // ceil(NN/256)

typedef __attribute__((ext_vector_type(8))) short bf16x8;
typedef __attribute__((ext_vector_type(4))) float f32x4;

static __device__ __forceinline__ short f2bf(float f) {
  union { float f; unsigned u; } v; v.f = f;
  unsigned r = (v.u + 0x7FFF + ((v.u >> 16) & 1)) >> 16;  // RNE
  return (short)r;
}
static __device__ __forceinline__ float bflo(unsigned p) {
  return __uint_as_float(p << 16);
}
static __device__ __forceinline__ float bfhi(unsigned p) {
  return __uint_as_float(p & 0xffff0000u);
}

// ---------------------------------------------------------------------------
// Prep: swizzle W (fp32 k x n row-major) into bf16 MFMA-B fragments and
// precompute BN scale/shift. B-frag for 16x16x32: lane = (n&15) + 16*quad,
// holds B[k = kb*32 + quad*8 + j][n], j=0..7 contiguous (16B per lane).
// ---------------------------------------------------------------------------
__global__ __launch_bounds__(256) void prep(
    const float* __restrict__ W, const float* __restrict__ gamma,
    const float* __restrict__ beta, const float* __restrict__ rmean,
    const float* __restrict__ rvar, short* __restrict__ Wsw,
    float* __restrict__ scsh) {
  const int t = threadIdx.x;
  for (int i = t; i < CC * CC; i += 256) {
    int k = i >> 7, n = i & 127;
    int nt = n >> 4, kb = k >> 5, q = (k >> 3) & 3, j = k & 7;
    int lane = (n & 15) + 16 * q;
    Wsw[(size_t)(((nt * 4 + kb) * 64 + lane) * 8 + j)] = f2bf(W[i]);
  }
  if (t < CC) {
    float sc = gamma[t] * rsqrtf(rvar[t] + BN_EPS);
    scsh[t] = sc;
    scsh[CC + t] = beta[t] - rmean[t] * sc;
  }
}

// ---------------------------------------------------------------------------
// MFMA linear: 64 rows/block, 4 waves x 16 rows, N=K=128 full.
// A-frags straight from global src (each byte read exactly once across grid);
// B-frags from Wsw (L1-resident 32KB). MODE 0: h=bf16(acc+b) -> hout (ws).
// MODE 1 (mid-tier): in-place on fout(=src): relu(BN(acc + bsel*b)), where
// src rows are premeaned agg (read-before-write within each wave's own rows).
// ---------------------------------------------------------------------------
template <int MODE>
__global__ __launch_bounds__(256) void linear_mfma(
    const float* __restrict__ src, const short* __restrict__ Wsw,
    const float* __restrict__ bias, const float* __restrict__ scsh,
    const int* __restrict__ off, short* __restrict__ hout,
    float* __restrict__ fout) {
  const int t = threadIdx.x;
  const int wave = t >> 6, lane = t & 63;
  const int quad = lane >> 4, m = lane & 15;
  const int rowbase = blockIdx.x * 64 + wave * 16;
  const int arow = rowbase + m;

  f32x4 acc[8];
#pragma unroll
  for (int nt = 0; nt < 8; ++nt) acc[nt] = (f32x4){0.f, 0.f, 0.f, 0.f};

#pragma unroll
  for (int kb = 0; kb < 4; ++kb) {
    bf16x8 a;
    if (arow < NN) {
      const float* p = src + (size_t)arow * CC + kb * 32 + quad * 8;
      float4 u = *(const float4*)p;
      float4 v = *(const float4*)(p + 4);
      a[0] = f2bf(u.x); a[1] = f2bf(u.y); a[2] = f2bf(u.z); a[3] = f2bf(u.w);
      a[4] = f2bf(v.x); a[5] = f2bf(v.y); a[6] = f2bf(v.z); a[7] = f2bf(v.w);
    } else {
#pragma unroll
      for (int j = 0; j < 8; ++j) a[j] = 0;
    }
#pragma unroll
    for (int nt = 0; nt < 8; ++nt) {
      bf16x8 b = *(const bf16x8*)(Wsw + (size_t)(((nt * 4 + kb) * 64 + lane) * 8));
      acc[nt] = __builtin_amdgcn_mfma_f32_16x16x32_bf16(a, b, acc[nt], 0, 0, 0);
    }
  }

  // D layout: col = lane&15 (=m) within n-tile, row = quad*4 + reg.
  if (MODE == 0) {
#pragma unroll
    for (int nt = 0; nt < 8; ++nt) {
      const int col = nt * 16 + m;
      const float bv = bias[col];
#pragma unroll
      for (int reg = 0; reg < 4; ++reg) {
        const int R = rowbase + quad * 4 + reg;
        if (R < NN) hout[(size_t)R * CC + col] = f2bf(acc[nt][reg] + bv);
      }
    }
  } else {
    float bsel[4];
#pragma unroll
    for (int reg = 0; reg < 4; ++reg) {
      const int R = rowbase + quad * 4 + reg;
      bsel[reg] = (R < NN && off[R + 1] > off[R]) ? 1.0f : 0.0f;
    }
#pragma unroll
    for (int nt = 0; nt < 8; ++nt) {
      const int col = nt * 16 + m;
      const float bv = bias[col], sc = scsh[col], sh = scsh[CC + col];
#pragma unroll
      for (int reg = 0; reg < 4; ++reg) {
        const int R = rowbase + quad * 4 + reg;
        if (R < NN) {
          float v = acc[nt][reg] + bsel[reg] * bv;
          fout[(size_t)R * CC + col] = fmaxf(0.f, v * sc + sh);
        }
      }
    }
  }
}

// ---------------------------------------------------------------------------
// CSR build: degree -> 3-kernel scan -> fill.
// ---------------------------------------------------------------------------
__global__ __launch_bounds__(256) void degree_count(const int* __restrict__ ei,
                                                    int* __restrict__ cnt) {
  int e = blockIdx.x * 256 + threadIdx.x;
  if (e >= NE) return;
  atomicAdd(cnt + ei[NE + e], 1);
}

__global__ __launch_bounds__(256) void scan1(const int* __restrict__ cnt,
                                             int* __restrict__ off,
                                             int* __restrict__ bsum) {
  __shared__ int sh[256];
  const int t = threadIdx.x;
  const int i = blockIdx.x * 256 + t;
  const int v = (i < NN) ? cnt[i] : 0;
  sh[t] = v;
  __syncthreads();
  for (int d = 1; d < 256; d <<= 1) {
    int add = (t >= d) ? sh[t - d] : 0;
    __syncthreads();
    sh[t] += add;
    __syncthreads();
  }
  if (i < NN) off[i] = sh[t] - v;
  if (t == 255) bsum[blockIdx.x] = sh[t];
}

__global__ __launch_bounds__(512) void scan2(int* __restrict__ bsum) {
  __shared__ int sh[512];
  const int t = threadIdx.x;
  const int v = (t < NB) ? bsum[t] : 0;
  sh[t] = v;
  __syncthreads();
  for (int d = 1; d < 512; d <<= 1) {
    int add = (t >= d) ? sh[t - d] : 0;
    __syncthreads();
    sh[t] += add;
    __syncthreads();
  }
  if (t < NB) bsum[t] = sh[t] - v;
}

// scan3 also writes the csr_fill cursor copy (saves a memcpy dispatch).
__global__ __launch_bounds__(256) void scan3(int* __restrict__ off,
                                             const int* __restrict__ bsum,
                                             int* __restrict__ cur) {
  const int i = blockIdx.x * 256 + threadIdx.x;
  if (i < NN) {
    int o = off[i] + bsum[blockIdx.x];
    off[i] = o;
    cur[i] = o;
  }
  if (i == 0) off[NN] = NE;
}

__global__ __launch_bounds__(256) void csr_fill(const int* __restrict__ ei,
                                                int* __restrict__ cursor,
                                                int* __restrict__ csr) {
  int e = blockIdx.x * 256 + threadIdx.x;
  if (e >= NE) return;
  int pos = atomicAdd(cursor + ei[NE + e], 1);
  csr[pos] = ei[e];
}

// ---------------------------------------------------------------------------
// Gather bf16 h rows (256B/edge), fused mean + BN + ReLU epilogue.
// One wave per dst node; lane owns channels (2l, 2l+1) -> one uint per row.
// ---------------------------------------------------------------------------
__global__ __launch_bounds__(256) void gather_bn_relu(
    const short* __restrict__ h, const int* __restrict__ off,
    const int* __restrict__ csr, const float* __restrict__ scsh,
    float* __restrict__ out) {
  const int node = (blockIdx.x * 256 + threadIdx.x) >> 6;
  const int lane = threadIdx.x & 63;
  if (node >= NN) return;
  const int s = off[node], e = off[node + 1];
  const unsigned* hb = (const unsigned*)h;

  float ax = 0.f, ay = 0.f;
  int i = s;
  for (; i + 3 < e; i += 4) {
    int s0 = csr[i], s1 = csr[i + 1], s2 = csr[i + 2], s3 = csr[i + 3];
    unsigned p0 = hb[(size_t)s0 * 64 + lane];
    unsigned p1 = hb[(size_t)s1 * 64 + lane];
    unsigned p2 = hb[(size_t)s2 * 64 + lane];
    unsigned p3 = hb[(size_t)s3 * 64 + lane];
    ax += (bflo(p0) + bflo(p1)) + (bflo(p2) + bflo(p3));
    ay += (bfhi(p0) + bfhi(p1)) + (bfhi(p2) + bfhi(p3));
  }
  for (; i < e; ++i) {
    unsigned p = hb[(size_t)csr[i] * 64 + lane];
    ax += bflo(p);
    ay += bfhi(p);
  }
  const float inv = (e > s) ? 1.0f / (float)(e - s) : 0.0f;
  const float2 sc = *(const float2*)(scsh + 2 * lane);
  const float2 sh = *(const float2*)(scsh + CC + 2 * lane);
  float2 o;
  o.x = fmaxf(0.f, ax * inv * sc.x + sh.x);
  o.y = fmaxf(0.f, ay * inv * sc.y + sh.y);
  *(float2*)(out + (size_t)node * CC + lane * 2) = o;
}

// ---------------------------------------------------------------------------
// Mid-tier gather (fp32 x -> premeaned agg in d_out), and last-tier fallback.
// ---------------------------------------------------------------------------
__global__ __launch_bounds__(256) void gather_mean(const float* __restrict__ x,
                                                   const int* __restrict__ off,
                                                   const int* __restrict__ csr,
                                                   float* __restrict__ agg) {
  const int wid = (blockIdx.x * 256 + threadIdx.x) >> 6;
  const int lane = threadIdx.x & 63;
  if (wid >= NN) return;
  const int s = off[wid], e = off[wid + 1];
  const float* xb = x + lane * 2;
  float2 acc = make_float2(0.f, 0.f);
  int i = s;
  for (; i + 1 < e; i += 2) {
    int s0 = csr[i], s1 = csr[i + 1];
    float2 a = *(const float2*)(xb + (size_t)s0 * CC);
    float2 b = *(const float2*)(xb + (size_t)s1 * CC);
    acc.x += a.x + b.x;
    acc.y += a.y + b.y;
  }
  if (i < e) {
    float2 a = *(const float2*)(xb + (size_t)csr[i] * CC);
    acc.x += a.x;
    acc.y += a.y;
  }
  const float inv = (e > s) ? 1.0f / (float)(e - s) : 0.0f;
  acc.x *= inv;
  acc.y *= inv;
  *(float2*)(agg + (size_t)wid * CC + lane * 2) = acc;
}

__global__ __launch_bounds__(256) void edge_scatter(
    const float* __restrict__ x, const int* __restrict__ ei,
    float* __restrict__ sums, int* __restrict__ cnt) {
  int gt = blockIdx.x * 256 + threadIdx.x;
  int e = gt >> 5;
  int sub = gt & 31;
  if (e >= NE) return;
  int src = ei[e];
  int dst = ei[NE + e];
  const float4 v = *(const float4*)(x + (size_t)src * CC + sub * 4);
  float* o = sums + (size_t)dst * CC + sub * 4;
  unsafeAtomicAdd(o + 0, v.x);
  unsafeAtomicAdd(o + 1, v.y);
  unsafeAtomicAdd(o + 2, v.z);
  unsafeAtomicAdd(o + 3, v.w);
  if (sub == 0) atomicAdd(cnt + dst, 1);
}

// Last-tier fp32 vector GEMM (sums in buf, divide by cnt here).
__global__ __launch_bounds__(256) void gemm_bn_relu_fb(
    float* buf, const float* __restrict__ W, const float* __restrict__ bias,
    const float* __restrict__ gamma, const float* __restrict__ beta,
    const float* __restrict__ rmean, const float* __restrict__ rvar,
    const int* __restrict__ cnt) {
  __shared__ float xsT[CC][65];
  const int t = threadIdx.x;
  const int n0 = blockIdx.x * 64;
  for (int j = 0; j < 8; ++j) {
    int i = t + 256 * j;
    int row = i >> 5;
    int ko = (i & 31) * 4;
    float4 v = make_float4(0.f, 0.f, 0.f, 0.f);
    if (n0 + row < NN) v = *(const float4*)(buf + (size_t)(n0 + row) * CC + ko);
    xsT[ko + 0][row] = v.x;
    xsT[ko + 1][row] = v.y;
    xsT[ko + 2][row] = v.z;
    xsT[ko + 3][row] = v.w;
  }
  __syncthreads();
  const int cg = t & 31;
  const int ng8 = (t >> 5) * 8;
  float acc[8][4];
#pragma unroll
  for (int j = 0; j < 8; ++j)
#pragma unroll
    for (int c = 0; c < 4; ++c) acc[j][c] = 0.f;
#pragma unroll 8
  for (int k = 0; k < CC; ++k) {
    const float4 wv = *(const float4*)(W + k * CC + cg * 4);
#pragma unroll
    for (int j = 0; j < 8; ++j) {
      const float xv = xsT[k][ng8 + j];
      acc[j][0] = fmaf(xv, wv.x, acc[j][0]);
      acc[j][1] = fmaf(xv, wv.y, acc[j][1]);
      acc[j][2] = fmaf(xv, wv.z, acc[j][2]);
      acc[j][3] = fmaf(xv, wv.w, acc[j][3]);
    }
  }
  const float4 bb = *(const float4*)(bias + cg * 4);
  const float4 gg = *(const float4*)(gamma + cg * 4);
  const float4 bt = *(const float4*)(beta + cg * 4);
  const float4 mu = *(const float4*)(rmean + cg * 4);
  const float4 vr = *(const float4*)(rvar + cg * 4);
  float sc[4], sh[4];
  sc[0] = gg.x * rsqrtf(vr.x + BN_EPS);
  sc[1] = gg.y * rsqrtf(vr.y + BN_EPS);
  sc[2] = gg.z * rsqrtf(vr.z + BN_EPS);
  sc[3] = gg.w * rsqrtf(vr.w + BN_EPS);
  sh[0] = bt.x - mu.x * sc[0];
  sh[1] = bt.y - mu.y * sc[1];
  sh[2] = bt.z - mu.z * sc[2];
  sh[3] = bt.w - mu.w * sc[3];
#pragma unroll
  for (int j = 0; j < 8; ++j) {
    const int n = n0 + ng8 + j;
    if (n >= NN) continue;
    const int cn = cnt[n];
    const float inv = cn > 0 ? 1.0f / (float)cn : 0.0f;
    const float bsel = cn > 0 ? 1.0f : 0.0f;
    float4 o;
    o.x = fmaxf(0.f, (acc[j][0] * inv + bsel * bb.x) * sc[0] + sh[0]);
    o.y = fmaxf(0.f, (acc[j][1] * inv + bsel * bb.y) * sc[1] + sh[1]);
    o.z = fmaxf(0.f, (acc[j][2] * inv + bsel * bb.z) * sc[2] + sh[2]);
    o.w = fmaxf(0.f, (acc[j][3] * inv + bsel * bb.w) * sc[3] + sh[3]);
    *(float4*)(buf + (size_t)n * CC + cg * 4) = o;
  }
}

extern "C" void kernel_launch(void* const* d_in, const int* in_sizes, int n_in,
                              void* d_out, int out_size, void* d_ws, size_t ws_size,
                              hipStream_t stream) {
  const float* x     = (const float*)d_in[0];
  const int*   ei    = (const int*)d_in[1];
  const float* W     = (const float*)d_in[2];
  const float* bias  = (const float*)d_in[3];
  const float* gamma = (const float*)d_in[4];
  const float* beta  = (const float*)d_in[5];
  const float* rmean = (const float*)d_in[6];
  const float* rvar  = (const float*)d_in[7];
  float* out = (float*)d_out;

  // ws layout (bytes):
  const size_t OFF_B  = 0;          // off[NN+1]
  const size_t CUR_B  = 400128;     // cursor[NN]
  const size_t BSUM_B = 800256;     // bsum[512]
  const size_t CSR_B  = 802304;     // csr[NE]
  const size_t SCSH_B = 7202304;    // scsh[256] fp32
  const size_t WSW_B  = 7203328;    // Wsw[128*128] bf16
  const size_t H_B    = 7236096;    // h[NN*CC] bf16
  const size_t NEED_A = 7236096;
  const size_t NEED_B = 32836096;

  if (ws_size >= NEED_A) {
    int*   off  = (int*)((char*)d_ws + OFF_B);
    int*   cur  = (int*)((char*)d_ws + CUR_B);
    int*   bsum = (int*)((char*)d_ws + BSUM_B);
    int*   csr  = (int*)((char*)d_ws + CSR_B);
    float* scsh = (float*)((char*)d_ws + SCSH_B);
    short* Wsw  = (short*)((char*)d_ws + WSW_B);

    prep<<<1, 256, 0, stream>>>(W, gamma, beta, rmean, rvar, Wsw, scsh);
    hipMemsetAsync(cur, 0, (size_t)NN * sizeof(int), stream);  // cnt
    degree_count<<<(NE + 255) / 256, 256, 0, stream>>>(ei, cur);
    scan1<<<NB, 256, 0, stream>>>(cur, off, bsum);
    scan2<<<1, 512, 0, stream>>>(bsum);
    scan3<<<NB, 256, 0, stream>>>(off, bsum, cur);
    csr_fill<<<(NE + 255) / 256, 256, 0, stream>>>(ei, cur, csr);

    if (ws_size >= NEED_B) {
      short* h = (short*)((char*)d_ws + H_B);
      linear_mfma<0><<<(NN + 63) / 64, 256, 0, stream>>>(
          x, Wsw, bias, scsh, off, h, nullptr);
      gather_bn_relu<<<(NN * 64 + 255) / 256, 256, 0, stream>>>(
          h, off, csr, scsh, out);
    } else {
      gather_mean<<<(NN * 64 + 255) / 256, 256, 0, stream>>>(x, off, csr, out);
      linear_mfma<1><<<(NN + 63) / 64, 256, 0, stream>>>(
          out, Wsw, bias, scsh, off, nullptr, out);
    }
  } else {
    int* cnt = (int*)d_ws;
    hipMemsetAsync(out, 0, (size_t)NN * CC * sizeof(float), stream);
    hipMemsetAsync(cnt, 0, (size_t)NN * sizeof(int), stream);
    edge_scatter<<<(NE * 32) / 256, 256, 0, stream>>>(x, ei, out, cnt);
    gemm_bn_relu_fb<<<(NN + 63) / 64, 256, 0, stream>>>(
        out, W, bias, gamma, beta, rmean, rvar, cnt);
  }
}

// Round 4
// 351.032 us; speedup vs baseline: 8.4282x; 1.1683x over previous
//
#include <hip/hip_runtime.h>

// GCN layer on MI355X — round 4.
//   prep_zero:         Wsw (bf16 MFMA-B swizzle), scsh (BN), cur=0    [391 blk]
//   linear_and_degree: h = bf16(x@W+b) via MFMA  +  degree histogram  [fused]
//   scan1 / scan3m:    exclusive scan of degrees -> off (+cursor copy)
//   csr_fill_part:     XCD-partitioned by dst -> csr lines fill in ONE
//                      XCD's L2 (round 3: 105MB written for 6.4MB csr = 16x
//                      partial-line RMW amplification, 123us)
//   gather_bn_relu:    out = relu(BN(mean(h[csr[dst]])))  (256B/edge bf16)
// mean(h[src]) = mean(x[src])@W + b (linearity); deg=0 -> sum=0 -> relu(sh).

#define NN 100000
#define NE 1600000
#define CC 128
#define BN_EPS 1e-5f
#define NB 391        // ceil(NN/256)
#define LBLK 1563     // ceil(NN/64) linear blocks
#define DBLK 1024     // degree blocks; 1024*1563 >= NE
#define DCHUNK 1563
#define FCHUNKS 256   // csr_fill chunks per partition; 256*6250 = NE
#define FCHUNK 6250
#define PARTN 12500   // NN/8 dst nodes per XCD partition

typedef __attribute__((ext_vector_type(8))) short bf16x8;
typedef __attribute__((ext_vector_type(4))) float f32x4;

static __device__ __forceinline__ short f2bf(float f) {
  union { float f; unsigned u; } v; v.f = f;
  unsigned r = (v.u + 0x7FFF + ((v.u >> 16) & 1)) >> 16;  // RNE
  return (short)r;
}
static __device__ __forceinline__ float bflo(unsigned p) {
  return __uint_as_float(p << 16);
}
static __device__ __forceinline__ float bfhi(unsigned p) {
  return __uint_as_float(p & 0xffff0000u);
}

// ---------------------------------------------------------------------------
// prep_zero: zero cursor/cnt, swizzle W into bf16 B-fragments, BN scale/shift.
// B-frag (16x16x32): lane = (n&15) + 16*quad holds B[kb*32+quad*8+j][n].
// ---------------------------------------------------------------------------
__global__ __launch_bounds__(256) void prep_zero(
    const float* __restrict__ W, const float* __restrict__ gamma,
    const float* __restrict__ beta, const float* __restrict__ rmean,
    const float* __restrict__ rvar, short* __restrict__ Wsw,
    float* __restrict__ scsh, int* __restrict__ cur) {
  const int i = blockIdx.x * 256 + threadIdx.x;
  if (i < NN) cur[i] = 0;
  if (i < CC * CC) {
    int k = i >> 7, n = i & 127;
    int nt = n >> 4, kb = k >> 5, q = (k >> 3) & 3, j = k & 7;
    int lane = (n & 15) + 16 * q;
    Wsw[(size_t)(((nt * 4 + kb) * 64 + lane) * 8 + j)] = f2bf(W[i]);
  }
  if (i < CC) {
    float sc = gamma[i] * rsqrtf(rvar[i] + BN_EPS);
    scsh[i] = sc;
    scsh[CC + i] = beta[i] - rmean[i] * sc;
  }
}

// ---------------------------------------------------------------------------
// Fused: blocks [0,LBLK) do the MFMA linear (h = bf16(x@W+b), 64 rows/block);
// blocks [LBLK, LBLK+DBLK) do the degree histogram. MFMA + atomic pipes
// co-schedule across CUs (m114: time ~ max, not sum).
// ---------------------------------------------------------------------------
__global__ __launch_bounds__(256) void linear_and_degree(
    const float* __restrict__ x, const short* __restrict__ Wsw,
    const float* __restrict__ bias, const int* __restrict__ ei,
    int* __restrict__ cnt, short* __restrict__ hout) {
  if (blockIdx.x >= LBLK) {
    const int c = blockIdx.x - LBLK;
    const int e0 = c * DCHUNK;
    const int e1 = min(NE, e0 + DCHUNK);
    for (int e = e0 + threadIdx.x; e < e1; e += 256)
      atomicAdd(cnt + ei[NE + e], 1);
    return;
  }
  const int t = threadIdx.x;
  const int wave = t >> 6, lane = t & 63;
  const int quad = lane >> 4, m = lane & 15;
  const int rowbase = blockIdx.x * 64 + wave * 16;
  const int arow = rowbase + m;

  f32x4 acc[8];
#pragma unroll
  for (int nt = 0; nt < 8; ++nt) acc[nt] = (f32x4){0.f, 0.f, 0.f, 0.f};

#pragma unroll
  for (int kb = 0; kb < 4; ++kb) {
    bf16x8 a;
    if (arow < NN) {
      const float* p = x + (size_t)arow * CC + kb * 32 + quad * 8;
      float4 u = *(const float4*)p;
      float4 v = *(const float4*)(p + 4);
      a[0] = f2bf(u.x); a[1] = f2bf(u.y); a[2] = f2bf(u.z); a[3] = f2bf(u.w);
      a[4] = f2bf(v.x); a[5] = f2bf(v.y); a[6] = f2bf(v.z); a[7] = f2bf(v.w);
    } else {
#pragma unroll
      for (int j = 0; j < 8; ++j) a[j] = 0;
    }
#pragma unroll
    for (int nt = 0; nt < 8; ++nt) {
      bf16x8 b = *(const bf16x8*)(Wsw + (size_t)(((nt * 4 + kb) * 64 + lane) * 8));
      acc[nt] = __builtin_amdgcn_mfma_f32_16x16x32_bf16(a, b, acc[nt], 0, 0, 0);
    }
  }
  // D layout: col = m within n-tile, row = quad*4 + reg.
#pragma unroll
  for (int nt = 0; nt < 8; ++nt) {
    const int col = nt * 16 + m;
    const float bv = bias[col];
#pragma unroll
    for (int reg = 0; reg < 4; ++reg) {
      const int R = rowbase + quad * 4 + reg;
      if (R < NN) hout[(size_t)R * CC + col] = f2bf(acc[nt][reg] + bv);
    }
  }
}

// ---------------------------------------------------------------------------
// scan1: per-block inclusive scan -> exclusive off + block totals.
// scan3m: each block reduces bsum[0..b) itself (kills the scan2 dispatch),
//         adds prefix, writes off and the csr_fill cursor copy.
// ---------------------------------------------------------------------------
__global__ __launch_bounds__(256) void scan1(const int* __restrict__ cnt,
                                             int* __restrict__ off,
                                             int* __restrict__ bsum) {
  __shared__ int sh[256];
  const int t = threadIdx.x;
  const int i = blockIdx.x * 256 + t;
  const int v = (i < NN) ? cnt[i] : 0;
  sh[t] = v;
  __syncthreads();
  for (int d = 1; d < 256; d <<= 1) {
    int add = (t >= d) ? sh[t - d] : 0;
    __syncthreads();
    sh[t] += add;
    __syncthreads();
  }
  if (i < NN) off[i] = sh[t] - v;
  if (t == 255) bsum[blockIdx.x] = sh[t];
}

__global__ __launch_bounds__(256) void scan3m(int* __restrict__ off,
                                              const int* __restrict__ bsum,
                                              int* __restrict__ cur) {
  __shared__ int sh[256];
  const int b = blockIdx.x, t = threadIdx.x;
  int s = 0;
  for (int j = t; j < b; j += 256) s += bsum[j];
  sh[t] = s;
  __syncthreads();
  for (int d = 128; d > 0; d >>= 1) {
    if (t < d) sh[t] += sh[t + d];
    __syncthreads();
  }
  const int pref = sh[0];
  const int i = b * 256 + t;
  if (i < NN) {
    int o = off[i] + pref;
    off[i] = o;
    cur[i] = o;
  }
  if (i == 0) off[NN] = NE;
}

// ---------------------------------------------------------------------------
// csr_fill, XCD-partitioned: p = blockIdx&7 (round-robin block->XCD
// heuristic); block only handles dst in [p*PARTN,(p+1)*PARTN), so every csr
// cache line is written by exactly one XCD and fills in its local L2 before
// write-back (round-3: 16x partial-line write amplification). Edge list is
// read 8x (102 MB) but LLC-resident. Heuristic affects speed only.
// ---------------------------------------------------------------------------
__global__ __launch_bounds__(256) void csr_fill_part(
    const int* __restrict__ ei, int* __restrict__ cursor,
    int* __restrict__ csr) {
  const int p = blockIdx.x & 7;
  const int c = blockIdx.x >> 3;
  const int lo = p * PARTN, hi = lo + PARTN;
  const int e0 = c * FCHUNK;
  const int e1 = e0 + FCHUNK;
  for (int e = e0 + threadIdx.x; e < e1; e += 256) {
    int dst = ei[NE + e];
    if (dst >= lo && dst < hi) {
      int pos = atomicAdd(cursor + dst, 1);
      csr[pos] = ei[e];
    }
  }
}

// ---------------------------------------------------------------------------
// Gather bf16 h rows (256B/edge), fused mean + BN + ReLU.
// One wave per dst node; lane owns channels (2l, 2l+1).
// ---------------------------------------------------------------------------
__global__ __launch_bounds__(256) void gather_bn_relu(
    const short* __restrict__ h, const int* __restrict__ off,
    const int* __restrict__ csr, const float* __restrict__ scsh,
    float* __restrict__ out) {
  const int node = (blockIdx.x * 256 + threadIdx.x) >> 6;
  const int lane = threadIdx.x & 63;
  if (node >= NN) return;
  const int s = off[node], e = off[node + 1];
  const unsigned* hb = (const unsigned*)h;

  float ax = 0.f, ay = 0.f;
  int i = s;
  for (; i + 3 < e; i += 4) {
    int s0 = csr[i], s1 = csr[i + 1], s2 = csr[i + 2], s3 = csr[i + 3];
    unsigned p0 = hb[(size_t)s0 * 64 + lane];
    unsigned p1 = hb[(size_t)s1 * 64 + lane];
    unsigned p2 = hb[(size_t)s2 * 64 + lane];
    unsigned p3 = hb[(size_t)s3 * 64 + lane];
    ax += (bflo(p0) + bflo(p1)) + (bflo(p2) + bflo(p3));
    ay += (bfhi(p0) + bfhi(p1)) + (bfhi(p2) + bfhi(p3));
  }
  for (; i < e; ++i) {
    unsigned p = hb[(size_t)csr[i] * 64 + lane];
    ax += bflo(p);
    ay += bfhi(p);
  }
  const float inv = (e > s) ? 1.0f / (float)(e - s) : 0.0f;
  const float2 sc = *(const float2*)(scsh + 2 * lane);
  const float2 sh = *(const float2*)(scsh + CC + 2 * lane);
  float2 o;
  o.x = fmaxf(0.f, ax * inv * sc.x + sh.x);
  o.y = fmaxf(0.f, ay * inv * sc.y + sh.y);
  *(float2*)(out + (size_t)node * CC + lane * 2) = o;
}

// ---------------------------------------------------------------------------
// Fallback (small ws): atomic scatter + fp32 vector GEMM.
// ---------------------------------------------------------------------------
__global__ __launch_bounds__(256) void edge_scatter(
    const float* __restrict__ x, const int* __restrict__ ei,
    float* __restrict__ sums, int* __restrict__ cnt) {
  int gt = blockIdx.x * 256 + threadIdx.x;
  int e = gt >> 5;
  int sub = gt & 31;
  if (e >= NE) return;
  int src = ei[e];
  int dst = ei[NE + e];
  const float4 v = *(const float4*)(x + (size_t)src * CC + sub * 4);
  float* o = sums + (size_t)dst * CC + sub * 4;
  unsafeAtomicAdd(o + 0, v.x);
  unsafeAtomicAdd(o + 1, v.y);
  unsafeAtomicAdd(o + 2, v.z);
  unsafeAtomicAdd(o + 3, v.w);
  if (sub == 0) atomicAdd(cnt + dst, 1);
}

__global__ __launch_bounds__(256) void gemm_bn_relu_fb(
    float* buf, const float* __restrict__ W, const float* __restrict__ bias,
    const float* __restrict__ gamma, const float* __restrict__ beta,
    const float* __restrict__ rmean, const float* __restrict__ rvar,
    const int* __restrict__ cnt) {
  __shared__ float xsT[CC][65];
  const int t = threadIdx.x;
  const int n0 = blockIdx.x * 64;
  for (int j = 0; j < 8; ++j) {
    int i = t + 256 * j;
    int row = i >> 5;
    int ko = (i & 31) * 4;
    float4 v = make_float4(0.f, 0.f, 0.f, 0.f);
    if (n0 + row < NN) v = *(const float4*)(buf + (size_t)(n0 + row) * CC + ko);
    xsT[ko + 0][row] = v.x;
    xsT[ko + 1][row] = v.y;
    xsT[ko + 2][row] = v.z;
    xsT[ko + 3][row] = v.w;
  }
  __syncthreads();
  const int cg = t & 31;
  const int ng8 = (t >> 5) * 8;
  float acc[8][4];
#pragma unroll
  for (int j = 0; j < 8; ++j)
#pragma unroll
    for (int c = 0; c < 4; ++c) acc[j][c] = 0.f;
#pragma unroll 8
  for (int k = 0; k < CC; ++k) {
    const float4 wv = *(const float4*)(W + k * CC + cg * 4);
#pragma unroll
    for (int j = 0; j < 8; ++j) {
      const float xv = xsT[k][ng8 + j];
      acc[j][0] = fmaf(xv, wv.x, acc[j][0]);
      acc[j][1] = fmaf(xv, wv.y, acc[j][1]);
      acc[j][2] = fmaf(xv, wv.z, acc[j][2]);
      acc[j][3] = fmaf(xv, wv.w, acc[j][3]);
    }
  }
  const float4 bb = *(const float4*)(bias + cg * 4);
  const float4 gg = *(const float4*)(gamma + cg * 4);
  const float4 bt = *(const float4*)(beta + cg * 4);
  const float4 mu = *(const float4*)(rmean + cg * 4);
  const float4 vr = *(const float4*)(rvar + cg * 4);
  float sc[4], sh[4];
  sc[0] = gg.x * rsqrtf(vr.x + BN_EPS);
  sc[1] = gg.y * rsqrtf(vr.y + BN_EPS);
  sc[2] = gg.z * rsqrtf(vr.z + BN_EPS);
  sc[3] = gg.w * rsqrtf(vr.w + BN_EPS);
  sh[0] = bt.x - mu.x * sc[0];
  sh[1] = bt.y - mu.y * sc[1];
  sh[2] = bt.z - mu.z * sc[2];
  sh[3] = bt.w - mu.w * sc[3];
#pragma unroll
  for (int j = 0; j < 8; ++j) {
    const int n = n0 + ng8 + j;
    if (n >= NN) continue;
    const int cn = cnt[n];
    const float inv = cn > 0 ? 1.0f / (float)cn : 0.0f;
    const float bsel = cn > 0 ? 1.0f : 0.0f;
    float4 o;
    o.x = fmaxf(0.f, (acc[j][0] * inv + bsel * bb.x) * sc[0] + sh[0]);
    o.y = fmaxf(0.f, (acc[j][1] * inv + bsel * bb.y) * sc[1] + sh[1]);
    o.z = fmaxf(0.f, (acc[j][2] * inv + bsel * bb.z) * sc[2] + sh[2]);
    o.w = fmaxf(0.f, (acc[j][3] * inv + bsel * bb.w) * sc[3] + sh[3]);
    *(float4*)(buf + (size_t)n * CC + cg * 4) = o;
  }
}

extern "C" void kernel_launch(void* const* d_in, const int* in_sizes, int n_in,
                              void* d_out, int out_size, void* d_ws, size_t ws_size,
                              hipStream_t stream) {
  const float* x     = (const float*)d_in[0];
  const int*   ei    = (const int*)d_in[1];
  const float* W     = (const float*)d_in[2];
  const float* bias  = (const float*)d_in[3];
  const float* gamma = (const float*)d_in[4];
  const float* beta  = (const float*)d_in[5];
  const float* rmean = (const float*)d_in[6];
  const float* rvar  = (const float*)d_in[7];
  float* out = (float*)d_out;

  // ws layout (bytes): off[NN+1] | cur[NN] | bsum[512] | csr[NE] | scsh | Wsw | h
  const size_t OFF_B  = 0;
  const size_t CUR_B  = 400128;
  const size_t BSUM_B = 800256;
  const size_t CSR_B  = 802304;
  const size_t SCSH_B = 7202304;
  const size_t WSW_B  = 7203328;
  const size_t H_B    = 7236096;
  const size_t NEED   = 32836096;

  if (ws_size >= NEED) {
    int*   off  = (int*)((char*)d_ws + OFF_B);
    int*   cur  = (int*)((char*)d_ws + CUR_B);
    int*   bsum = (int*)((char*)d_ws + BSUM_B);
    int*   csr  = (int*)((char*)d_ws + CSR_B);
    float* scsh = (float*)((char*)d_ws + SCSH_B);
    short* Wsw  = (short*)((char*)d_ws + WSW_B);
    short* h    = (short*)((char*)d_ws + H_B);

    prep_zero<<<NB, 256, 0, stream>>>(W, gamma, beta, rmean, rvar, Wsw, scsh, cur);
    linear_and_degree<<<LBLK + DBLK, 256, 0, stream>>>(x, Wsw, bias, ei, cur, h);
    scan1<<<NB, 256, 0, stream>>>(cur, off, bsum);
    scan3m<<<NB, 256, 0, stream>>>(off, bsum, cur);
    csr_fill_part<<<FCHUNKS * 8, 256, 0, stream>>>(ei, cur, csr);
    gather_bn_relu<<<(NN * 64 + 255) / 256, 256, 0, stream>>>(h, off, csr, scsh, out);
  } else {
    int* cnt = (int*)d_ws;
    hipMemsetAsync(out, 0, (size_t)NN * CC * sizeof(float), stream);
    hipMemsetAsync(cnt, 0, (size_t)NN * sizeof(int), stream);
    edge_scatter<<<(NE * 32) / 256, 256, 0, stream>>>(x, ei, out, cnt);
    gemm_bn_relu_fb<<<(NN + 63) / 64, 256, 0, stream>>>(
        out, W, bias, gamma, beta, rmean, rvar, cnt);
  }
}